// Round 8
// baseline (216.764 us; speedup 1.0000x reference)
//
#include <hip/hip_runtime.h>
#include <math.h>

#define NB 32
#define CC 1024
#define SS 784
#define SP 832           // padded S (52*16); pad region of sa is zeroed
#define DD 128
#define KK 64
#define OUTD 1024
#define KD 8192          // K*D
#define PSPLIT 32        // split-K for projection (8192 = 32*256)

// workspace layout (BYTE offsets)  -- total ~15.6 MB
#define OFF_XN    0                                   // bf16 (N,D,SP)
#define OFF_SA    (OFF_XN + NB*DD*SP*2)               // bf16 (N,K,SP)
#define OFF_WPK   (OFF_SA + NB*KK*SP*2)               // bf16 Wpool frag-packed (32*8*64*8)
#define OFF_WCK   (OFF_WPK + 32*8*64*8*2)             // bf16 Wconv frag-packed (16*64*8)
#define OFF_VLADN (OFF_WCK + 16*64*8*2)               // f32 (N,KD)
#define OFF_OUTP  (OFF_VLADN + NB*KD*4)               // f32 (PSPLIT,N,OUT)

typedef __attribute__((ext_vector_type(8))) short bf16x8;   // 8 bf16 = 4 VGPRs
typedef __attribute__((ext_vector_type(4))) float f32x4;
typedef __attribute__((ext_vector_type(4))) unsigned int u32x4;

__device__ __forceinline__ unsigned int pk_bf16(float a, float b) {
    unsigned int ua = __builtin_bit_cast(unsigned int, a);
    unsigned int ub = __builtin_bit_cast(unsigned int, b);
    ua += 0x7FFFu + ((ua >> 16) & 1u);
    ub += 0x7FFFu + ((ub >> 16) & 1u);
    return (ua >> 16) | (ub & 0xFFFF0000u);
}
__device__ __forceinline__ unsigned short f2bf(float a) {
    unsigned int ua = __builtin_bit_cast(unsigned int, a);
    ua += 0x7FFFu + ((ua >> 16) & 1u);
    return (unsigned short)(ua >> 16);
}
__device__ __forceinline__ float bf2f(unsigned short u) {
    unsigned int v = ((unsigned int)u) << 16;
    return __builtin_bit_cast(float, v);
}

// ---------------------------------------------------------------------------
// c-permutation shared by pack_weights and pool staging:
// cb (0..127 = c-block of 8), elem j (0..7):
//   c = (cb>>5)*256 + ((cb>>3)&3)*64 + (cb&7) + 8*j
// GEMM contraction order over c is free as long as Wpk uses the SAME perm.
// ---------------------------------------------------------------------------

// ---------------------------------------------------------------------------
// K1 v5: pack Wpool/Wconv into MFMA A-fragment order.  Grid (9, 8).
// ---------------------------------------------------------------------------
__global__ __launch_bounds__(256)
void pack_weights(const float* __restrict__ Wpool, const float* __restrict__ Wconv,
                  unsigned short* __restrict__ Wpk, unsigned short* __restrict__ Wck)
{
    const int b = blockIdx.x;
    const int t = threadIdx.x;
    if (b < 8) {
        const int i = blockIdx.y;              // 0..7
        const int id = t + 256 * i;            // 0..2047
        const int ktl = id >> 9;               // 0..3
        const int mt  = (id >> 6) & 7;
        const int l   = id & 63;
        const int lm = l & 15, quad = l >> 4;
        const int kt = b * 4 + ktl;
        const int d = mt * 16 + lm;
        const int cb = kt * 4 + quad;          // 0..127
        const int base_c = (cb >> 5) * 256 + ((cb >> 3) & 3) * 64 + (cb & 7);
        float v[8];
#pragma unroll
        for (int j = 0; j < 8; j++) v[j] = Wpool[(size_t)d * CC + base_c + 8 * j];
        unsigned int* dst = (unsigned int*)&Wpk[(size_t)((kt * 8 + mt) * 64 + l) * 8];
        dst[0] = pk_bf16(v[0], v[1]); dst[1] = pk_bf16(v[2], v[3]);
        dst[2] = pk_bf16(v[4], v[5]); dst[3] = pk_bf16(v[6], v[7]);
    } else if (blockIdx.y < 4) {
        const int i = blockIdx.y;              // 0..3
        const int id = t + 256 * i;            // 0..1023
        const int tile = id >> 6;
        const int l = id & 63;
        const int lm = l & 15, quad = l >> 4;
        const int k = (tile >> 2) * 16 + lm;
        const int d = (tile & 3) * 32 + quad * 8;
        const float4 v0 = *(const float4*)&Wconv[(size_t)k * DD + d];
        const float4 v1 = *(const float4*)&Wconv[(size_t)k * DD + d + 4];
        unsigned int* dst = (unsigned int*)&Wck[(size_t)(tile * 64 + l) * 8];
        dst[0] = pk_bf16(v0.x, v0.y); dst[1] = pk_bf16(v0.z, v0.w);
        dst[2] = pk_bf16(v1.x, v1.y); dst[3] = pk_bf16(v1.z, v1.w);
    }
}

// ---------------------------------------------------------------------------
// K2 v5 (unchanged): pool GEMM + bias + L2-norm + assign GEMM + softmax.
// LDS 33.25 KB via aliasing; 4 blocks/CU; sched_barrier fences pin
// issue-early/consume-late staging.  NOTE: VGPR-quantization-capped at
// 16 waves/CU (needs >64 VGPR) — this is its structural occupancy floor.
// ---------------------------------------------------------------------------
__global__ __launch_bounds__(256, 4)
void pool_norm_assign(const float* __restrict__ x, const unsigned short* __restrict__ Wpk,
                      const float* __restrict__ bpool, const unsigned short* __restrict__ Wck,
                      const float* __restrict__ bconv,
                      unsigned short* __restrict__ xn, unsigned short* __restrict__ sa)
{
    const int n  = blockIdx.y;
    const int s0 = blockIdx.x * 32;
    const int t  = threadIdx.x;
    const int l  = t & 63;
    const int w  = t >> 6;       // wave 0..3
    const int lm = l & 15;
    const int quad = l >> 4;

    // 33.25 KB total: Bst0 (16 KB) | Bst1 (16 KB) | red/sums (1 KB)
    __shared__ alignas(16) unsigned char smem[2 * 32 * 32 * 8 * 2 + 4 * 32 * 4];
    unsigned short* Bst0 = (unsigned short*)smem;
    unsigned short* Bst1 = Bst0 + 32 * 32 * 8;
    unsigned short* xnT  = Bst0;                      // alias (see header)
    float* red  = (float*)(smem + 2 * 32 * 32 * 8 * 2);  // [4][32]
    float* sums = red;                                   // alias (see header)

    unsigned short* xnp = xn + (size_t)n * DD * SP;
    unsigned short* sap = sa + (size_t)n * KK * SP;

    if (s0 >= SS) {
        // pure-pad tile (s0 = 800): zero xn and sa for s 800..831, exit.
        const u32x4 z = (u32x4){0u, 0u, 0u, 0u};
#pragma unroll
        for (int pp = 0; pp < 2; pp++) {
            const int idx = t + 256 * pp;
            *(u32x4*)&xnp[(size_t)(idx >> 2) * SP + s0 + (idx & 3) * 8] = z;
        }
        *(u32x4*)&sap[(size_t)(t >> 2) * SP + s0 + (t & 3) * 8] = z;
        return;
    }

    const int r0 = (l >> 3) & 7;   // row-in-group 0..7
    const int se = l & 7;          // 16B s-chunk 0..7
    // chunk-aligned clamp for the mixed tile 24 (s 784..799 OOB -> reload
    // an in-bounds chunk; values garbage-but-finite, neutralized by sa=0)
    int sc = s0 + se * 4;
    if (sc + 4 > SS) sc = s0 + (se & 3) * 4;
    const float* xw = x + (size_t)n * CC * SS + sc;
    const int crow0 = w * 64 + r0;                 // + q*256 + j*8 = global c row

    // ---- prologue: issue quarter-0 x loads + Wpk depth-4 prefetch, THEN pack
    f32x4 g[8];
#pragma unroll
    for (int j = 0; j < 8; j++)
        g[j] = *(const f32x4*)&xw[(size_t)(crow0 + j * 8) * SS];

    bf16x8 abuf[4][2];  // prefetch depth 4: slot kt&3
#pragma unroll
    for (int p = 0; p < 4; p++)
#pragma unroll
        for (int i = 0; i < 2; i++)
            abuf[p][i] = *(const bf16x8*)&Wpk[(size_t)((p * 8 + w * 2 + i) * 64 + l) * 8];

    __builtin_amdgcn_sched_barrier(0);

#pragma unroll
    for (int ss = 0; ss < 4; ss++) {
        const int s = se * 4 + ss;
        const int sig = s ^ ((s >> 3) & 3);
        unsigned int* dst = (unsigned int*)&Bst0[(size_t)((w * 8 + r0) * 32 + sig) * 8];
        dst[0] = pk_bf16(g[0][ss], g[1][ss]); dst[1] = pk_bf16(g[2][ss], g[3][ss]);
        dst[2] = pk_bf16(g[4][ss], g[5][ss]); dst[3] = pk_bf16(g[6][ss], g[7][ss]);
    }
    __syncthreads();

    f32x4 acc[2][2];   // [i=d-tile][h=s-sub]
#pragma unroll
    for (int i = 0; i < 2; i++)
#pragma unroll
        for (int h = 0; h < 2; h++) acc[i][h] = (f32x4){0.f, 0.f, 0.f, 0.f};

    for (int q = 0; q < 4; ++q) {
        // issue next-quarter x loads (consumed only after this K-loop)
        if (q < 3) {
#pragma unroll
            for (int j = 0; j < 8; j++)
                g[j] = *(const f32x4*)&xw[(size_t)((q + 1) * 256 + crow0 + j * 8) * SS];
        }
        __builtin_amdgcn_sched_barrier(0);   // loads stay ABOVE the K-loop
        const unsigned short* Bq = (q & 1) ? Bst1 : Bst0;
#pragma unroll
        for (int ktq = 0; ktq < 8; ++ktq) {
            const int kt = q * 8 + ktq;
            const bf16x8 a0 = abuf[ktq & 3][0], a1 = abuf[ktq & 3][1];
            if (kt < 28) {
#pragma unroll
                for (int i = 0; i < 2; i++)
                    abuf[ktq & 3][i] = *(const bf16x8*)&Wpk[(size_t)(((kt + 4) * 8 + w * 2 + i) * 64 + l) * 8];
            }
#pragma unroll
            for (int h = 0; h < 2; h++) {
                const int s = h * 16 + lm;
                const int sig = s ^ ((s >> 3) & 3);
                const bf16x8 bf = *(const bf16x8*)&Bq[(size_t)((ktq * 4 + quad) * 32 + sig) * 8];
                acc[0][h] = __builtin_amdgcn_mfma_f32_16x16x32_bf16(a0, bf, acc[0][h], 0, 0, 0);
                acc[1][h] = __builtin_amdgcn_mfma_f32_16x16x32_bf16(a1, bf, acc[1][h], 0, 0, 0);
            }
        }
        __builtin_amdgcn_sched_barrier(0);   // packs stay BELOW the K-loop
        if (q < 3) {
            unsigned short* Bn = ((q + 1) & 1) ? Bst1 : Bst0;
#pragma unroll
            for (int ss = 0; ss < 4; ss++) {
                const int s = se * 4 + ss;
                const int sig = s ^ ((s >> 3) & 3);
                unsigned int* dst = (unsigned int*)&Bn[(size_t)((w * 8 + r0) * 32 + sig) * 8];
                dst[0] = pk_bf16(g[0][ss], g[1][ss]); dst[1] = pk_bf16(g[2][ss], g[3][ss]);
                dst[2] = pk_bf16(g[4][ss], g[5][ss]); dst[3] = pk_bf16(g[6][ss], g[7][ss]);
            }
        }
        __syncthreads();
    }

    // ---- PHASE 3a: bias + L2-norm over d.  C: d=(2w+i)*16+quad*4+r, s=h*16+lm
    float vals[2][2][4];
    float ssq[2] = {0.f, 0.f};
#pragma unroll
    for (int i = 0; i < 2; i++)
#pragma unroll
        for (int h = 0; h < 2; h++)
#pragma unroll
            for (int r = 0; r < 4; r++) {
                const int d = (w * 2 + i) * 16 + quad * 4 + r;
                const float v = acc[i][h][r] + bpool[d];
                vals[i][h][r] = v; ssq[h] += v * v;
            }
#pragma unroll
    for (int h = 0; h < 2; h++) {
        ssq[h] += __shfl_xor(ssq[h], 16, 64);
        ssq[h] += __shfl_xor(ssq[h], 32, 64);
    }
    if (quad == 0) { red[w * 32 + lm] = ssq[0]; red[w * 32 + 16 + lm] = ssq[1]; }
    __syncthreads();
    float scale[2];
#pragma unroll
    for (int h = 0; h < 2; h++) {
        const int sl = h * 16 + lm;
        scale[h] = 1.f / fmaxf(sqrtf(red[0 * 32 + sl] + red[1 * 32 + sl] + red[2 * 32 + sl] + red[3 * 32 + sl]), 1e-12f);
    }
    // red reads complete here for all threads before the next barrier;
    // xnT (aliasing Bst0, last read 2 barriers ago) is written now.
#pragma unroll
    for (int i = 0; i < 2; i++)
#pragma unroll
        for (int h = 0; h < 2; h++)
#pragma unroll
            for (int r = 0; r < 4; r++) {
                const int d = (w * 2 + i) * 16 + quad * 4 + r;
                const int sg = s0 + h * 16 + lm;
                const float v = vals[i][h][r] * scale[h];
                xnp[(size_t)d * SP + sg] = f2bf(v);
                xnT[(size_t)(((d >> 3) * 32) + h * 16 + lm) * 8 + (d & 7)] = f2bf(v);
            }
    __syncthreads();

    // ---- PHASE 3b: assign GEMM (64k x 32s), wave w -> k-tile w
    f32x4 acc2[2];
    acc2[0] = (f32x4){0.f, 0.f, 0.f, 0.f};
    acc2[1] = (f32x4){0.f, 0.f, 0.f, 0.f};
#pragma unroll
    for (int dsv = 0; dsv < 4; dsv++) {
        const bf16x8 afrag = *(const bf16x8*)&Wck[(size_t)((w * 4 + dsv) * 64 + l) * 8];
#pragma unroll
        for (int h = 0; h < 2; h++) {
            const bf16x8 bfrag = *(const bf16x8*)&xnT[(size_t)((dsv * 4 + quad) * 32 + h * 16 + lm) * 8];
            acc2[h] = __builtin_amdgcn_mfma_f32_16x16x32_bf16(afrag, bfrag, acc2[h], 0, 0, 0);
        }
    }
    // softmax over k (|logits| small since x-hat unit-norm: no max-sub needed)
    float e[2][4]; float ps[2] = {0.f, 0.f};
#pragma unroll
    for (int h = 0; h < 2; h++)
#pragma unroll
        for (int r = 0; r < 4; r++) {
            const int k = w * 16 + quad * 4 + r;
            e[h][r] = expf(acc2[h][r] + bconv[k]);
            ps[h] += e[h][r];
        }
#pragma unroll
    for (int h = 0; h < 2; h++) {
        ps[h] += __shfl_xor(ps[h], 16, 64);
        ps[h] += __shfl_xor(ps[h], 32, 64);
    }
    if (quad == 0) { sums[w * 32 + lm] = ps[0]; sums[w * 32 + 16 + lm] = ps[1]; }
    __syncthreads();
#pragma unroll
    for (int h = 0; h < 2; h++) {
        const int sl = h * 16 + lm;
        const int sg = s0 + sl;
        const float inv = 1.f / (sums[0 * 32 + sl] + sums[1 * 32 + sl] + sums[2 * 32 + sl] + sums[3 * 32 + sl]);
        const bool val2 = sg < SS;
#pragma unroll
        for (int r = 0; r < 4; r++) {
            const int k = w * 16 + quad * 4 + r;
            sap[(size_t)k * SP + sg] = val2 ? f2bf(e[h][r] * inv) : (unsigned short)0;
        }
    }
}

// ---------------------------------------------------------------------------
// K3 v7 (vlad_full): 512 threads, s-split.  Wave (kt, sh): kt = k-tile 0..3,
// sh = s-half 0..1 (13 of 26 s-steps each) -> 8 waves/block = 2x the TLP of
// the R7 version (which ran 4 waves at 1 block/CU).  sh=1 partials combined
// via LDS.  Named 2-deep ping-pong (no indexed arrays).  Summation order:
// two 13-chains + add (was one 26-chain) — within tolerance.
// ---------------------------------------------------------------------------
__global__ __launch_bounds__(512)
void vlad_full(const unsigned short* __restrict__ xn, const unsigned short* __restrict__ sa,
               const float* __restrict__ centroids, float* __restrict__ vladn)
{
    const int dg = blockIdx.x;     // 0..7, d = dg*16 + lm
    const int n  = blockIdx.y;
    const int t  = threadIdx.x;
    const int l  = t & 63;
    const int w8 = t >> 6;         // 0..7
    const int kt = w8 & 3;         // k-tile
    const int sh = w8 >> 2;        // s-half
    const int lm = l & 15, quad = l >> 4;

    __shared__ float sas[KK];
    __shared__ float red[4][16];
    __shared__ alignas(16) float accb[4][64][4];   // sh=1 partial acc
    __shared__ float ssb[4][16];                   // sh=1 partial ssum

    const unsigned short* sap = sa + (size_t)n * KK * SP + (size_t)(kt * 16 + lm) * SP + sh * 13 * 32 + quad * 8;
    const unsigned short* xnp = xn + (size_t)n * DD * SP + (size_t)(dg * 16 + lm) * SP + sh * 13 * 32 + quad * 8;

    f32x4 acc = (f32x4){0.f, 0.f, 0.f, 0.f};
    float ssum = 0.f;

    bf16x8 afA, bfA, afB, bfB;     // named 2-stage ping-pong over 13 steps
    afA = *(const bf16x8*)&sap[0];
    bfA = *(const bf16x8*)&xnp[0];
    afB = *(const bf16x8*)&sap[32];
    bfB = *(const bf16x8*)&xnp[32];
    __builtin_amdgcn_sched_barrier(0);

#pragma unroll
    for (int st = 0; st < 13; st += 2) {
        const bf16x8 a0 = afA, b0 = bfA;
        if (st + 2 < 13) {
            afA = *(const bf16x8*)&sap[(st + 2) * 32];
            bfA = *(const bf16x8*)&xnp[(st + 2) * 32];
        }
        acc = __builtin_amdgcn_mfma_f32_16x16x32_bf16(a0, b0, acc, 0, 0, 0);
#pragma unroll
        for (int j = 0; j < 8; j++) ssum += bf2f((unsigned short)a0[j]);

        if (st + 1 < 13) {
            const bf16x8 a1 = afB, b1 = bfB;
            if (st + 3 < 13) {
                afB = *(const bf16x8*)&sap[(st + 3) * 32];
                bfB = *(const bf16x8*)&xnp[(st + 3) * 32];
            }
            acc = __builtin_amdgcn_mfma_f32_16x16x32_bf16(a1, b1, acc, 0, 0, 0);
#pragma unroll
            for (int j = 0; j < 8; j++) ssum += bf2f((unsigned short)a1[j]);
        }
    }

    // row-total over this half's 13*32 s (all quads equal after the shfls)
    ssum += __shfl_xor(ssum, 16, 64);
    ssum += __shfl_xor(ssum, 32, 64);

    if (sh == 1) {
        *(f32x4*)&accb[kt][l][0] = acc;
        if (quad == 0) ssb[kt][lm] = ssum;
    }
    __syncthreads();

    float v[4];
    if (sh == 0) {
        const f32x4 p = *(const f32x4*)&accb[kt][l][0];
        acc += p;
        ssum += ssb[kt][lm];
        if (quad == 0) sas[kt * 16 + lm] = ssum;   // wave-local write/read

        float ssq = 0.f;
        const int d = dg * 16 + lm;
#pragma unroll
        for (int r = 0; r < 4; r++) {
            const int k = kt * 16 + quad * 4 + r;
            v[r] = acc[r] - centroids[(size_t)k * DD + d] * sas[k];
            ssq += v[r] * v[r];
        }
        ssq += __shfl_xor(ssq, 16, 64);
        ssq += __shfl_xor(ssq, 32, 64);
        if (quad == 0) red[kt][lm] = ssq;
    }
    __syncthreads();

    if (sh == 0) {
        const int d = dg * 16 + lm;
        const float tot = red[0][lm] + red[1][lm] + red[2][lm] + red[3][lm];
        const float scale = 1.f / fmaxf(sqrtf(tot), 1e-12f);
        float* vo = vladn + (size_t)n * KD;
#pragma unroll
        for (int r = 0; r < 4; r++) {
            const int k = kt * 16 + quad * 4 + r;
            vo[(size_t)k * DD + d] = v[r] * scale;
        }
    }
}

// ---------------------------------------------------------------------------
// K5: projection via MFMA.  PSPLIT 32 (2 blocks/CU, 2x TLP vs PSPLIT 16);
// 8 K-steps of 32 c with the 2-stage LA/LB pipeline.  grid (16,32) = 512.
// ---------------------------------------------------------------------------
#define PROJ_ISSUE(L, KT) do {                                              \
    const int c_ = (KT) * 32;                                               \
    L[0] = *(const f32x4*)&wrow[c_];  L[1] = *(const f32x4*)&wrow[c_ + 4];  \
    L[2] = *(const f32x4*)&arow0[c_]; L[3] = *(const f32x4*)&arow0[c_ + 4]; \
    L[4] = *(const f32x4*)&arow1[c_]; L[5] = *(const f32x4*)&arow1[c_ + 4]; \
} while (0)

#define PROJ_STEP(L) do {                                                    \
    union { unsigned int u[4]; bf16x8 v; } ub, ua0, ua1;                     \
    ub.u[0]  = pk_bf16(L[0][0], L[0][1]); ub.u[1]  = pk_bf16(L[0][2], L[0][3]); \
    ub.u[2]  = pk_bf16(L[1][0], L[1][1]); ub.u[3]  = pk_bf16(L[1][2], L[1][3]); \
    ua0.u[0] = pk_bf16(L[2][0], L[2][1]); ua0.u[1] = pk_bf16(L[2][2], L[2][3]); \
    ua0.u[2] = pk_bf16(L[3][0], L[3][1]); ua0.u[3] = pk_bf16(L[3][2], L[3][3]); \
    ua1.u[0] = pk_bf16(L[4][0], L[4][1]); ua1.u[1] = pk_bf16(L[4][2], L[4][3]); \
    ua1.u[2] = pk_bf16(L[5][0], L[5][1]); ua1.u[3] = pk_bf16(L[5][2], L[5][3]); \
    acc[0] = __builtin_amdgcn_mfma_f32_16x16x32_bf16(ua0.v, ub.v, acc[0], 0, 0, 0); \
    acc[1] = __builtin_amdgcn_mfma_f32_16x16x32_bf16(ua1.v, ub.v, acc[1], 0, 0, 0); \
} while (0)

__global__ __launch_bounds__(256)
void proj_mfma(const float* __restrict__ vladn, const float* __restrict__ Wproj,
               float* __restrict__ outp)
{
    const int o0 = blockIdx.x * 64;
    const int c0 = blockIdx.y * (KD / PSPLIT);   // 256-wide c slice
    const int t  = threadIdx.x;
    const int l  = t & 63;
    const int w  = t >> 6;
    const int lm = l & 15, quad = l >> 4;
    const int o  = o0 + w * 16 + lm;

    const float* wrow  = &Wproj[(size_t)o * KD + c0 + quad * 8];
    const float* arow0 = &vladn[(size_t)lm * KD + c0 + quad * 8];
    const float* arow1 = &vladn[(size_t)(16 + lm) * KD + c0 + quad * 8];

    f32x4 acc[2];
    acc[0] = (f32x4){0.f, 0.f, 0.f, 0.f};
    acc[1] = (f32x4){0.f, 0.f, 0.f, 0.f};

    f32x4 LA[6], LB[6];
    PROJ_ISSUE(LA, 0);
#pragma unroll
    for (int kt = 0; kt < 8; kt += 2) {
        PROJ_ISSUE(LB, kt + 1);
        __builtin_amdgcn_sched_barrier(0);
        PROJ_STEP(LA);
        if (kt + 2 < 8) PROJ_ISSUE(LA, kt + 2);
        __builtin_amdgcn_sched_barrier(0);
        PROJ_STEP(LB);
    }

    // C layout: col lm -> o (matches B), row quad*4+r -> n = a*16+quad*4+r
#pragma unroll
    for (int a = 0; a < 2; a++)
#pragma unroll
        for (int r = 0; r < 4; r++) {
            const int nn = a * 16 + quad * 4 + r;
            outp[((size_t)blockIdx.y * NB + nn) * OUTD + o] = acc[a][r];
        }
}

// ---------------------------------------------------------------------------
// K6: sum projection partials + bproj, final L2 norm over OUT, write d_out.
// PSPLIT=32: partial loads batched 16-at-a-time; add order preserved.
// ---------------------------------------------------------------------------
__global__ __launch_bounds__(256)
void final_norm_kernel(const float* __restrict__ outp, const float* __restrict__ bproj,
                       float* __restrict__ out)
{
    const int n = blockIdx.x;
    const int t = threadIdx.x;
    const int o4 = t * 4;

    float4 a = *(const float4*)&bproj[o4];
    f32x4 pr[16];
#pragma unroll
    for (int b = 0; b < 2; b++) {
#pragma unroll
        for (int i = 0; i < 16; i++)
            pr[i] = *(const f32x4*)&outp[((size_t)(b * 16 + i) * NB + n) * OUTD + o4];
        __builtin_amdgcn_sched_barrier(0);
#pragma unroll
        for (int i = 0; i < 16; i++) {
            a.x += pr[i][0]; a.y += pr[i][1]; a.z += pr[i][2]; a.w += pr[i][3];
        }
    }
    float ssp = a.x * a.x + a.y * a.y + a.z * a.z + a.w * a.w;
#pragma unroll
    for (int off = 32; off > 0; off >>= 1) ssp += __shfl_down(ssp, off, 64);
    __shared__ float rs[4];
    if ((t & 63) == 0) rs[t >> 6] = ssp;
    __syncthreads();
    const float total = rs[0] + rs[1] + rs[2] + rs[3];
    const float scale = 1.f / fmaxf(sqrtf(total), 1e-12f);
    float4 o;
    o.x = a.x * scale; o.y = a.y * scale; o.z = a.z * scale; o.w = a.w * scale;
    *(float4*)&out[(size_t)n * OUTD + o4] = o;
}

// ---------------------------------------------------------------------------
extern "C" void kernel_launch(void* const* d_in, const int* in_sizes, int n_in,
                              void* d_out, int out_size, void* d_ws, size_t ws_size,
                              hipStream_t stream)
{
    const float* x         = (const float*)d_in[0];
    const float* Wpool     = (const float*)d_in[1];
    const float* bpool     = (const float*)d_in[2];
    const float* Wconv     = (const float*)d_in[3];
    const float* bconv     = (const float*)d_in[4];
    const float* centroids = (const float*)d_in[5];
    const float* Wproj     = (const float*)d_in[6];
    const float* bproj     = (const float*)d_in[7];
    float* out = (float*)d_out;
    char*  wsb = (char*)d_ws;

    unsigned short* xn     = (unsigned short*)(wsb + OFF_XN);
    unsigned short* sa     = (unsigned short*)(wsb + OFF_SA);
    unsigned short* Wpk    = (unsigned short*)(wsb + OFF_WPK);
    unsigned short* Wck    = (unsigned short*)(wsb + OFF_WCK);
    float*          vladn  = (float*)(wsb + OFF_VLADN);
    float*          outp   = (float*)(wsb + OFF_OUTP);

    pack_weights<<<dim3(9, 8), 256, 0, stream>>>(Wpool, Wconv, Wpk, Wck);
    pool_norm_assign<<<dim3(26, NB), 256, 0, stream>>>(x, Wpk, bpool, Wck, bconv, xn, sa);
    vlad_full<<<dim3(DD / 16, NB), 512, 0, stream>>>(xn, sa, centroids, vladn);
    proj_mfma<<<dim3(OUTD / 64, PSPLIT), 256, 0, stream>>>(vladn, Wproj, outp);
    final_norm_kernel<<<dim3(NB), 256, 0, stream>>>(outp, bproj, out);
}